// Round 3
// baseline (6580.499 us; speedup 1.0000x reference)
//
#include <hip/hip_runtime.h>
#include <hip/hip_bf16.h>

// B=8 S=1024 C=512 V=512 D=512 NC=512 NF=2 H=8 TAU=1
// d_out is FLOAT32: [logp 4194304][z 1048576][diff 1][ids 2048]
// ws: S0,S1,S2 (8192x512 f32) + QKV chunk (1024x1536) + tail ≈ 54.6 MB.

static constexpr size_t SLOT = 4194304; // 8192*512 floats

__device__ __forceinline__ float eluf(float x) { return x > 0.f ? x : expm1f(x); }

// Weight index modes:
//  wmode 0: widx = o*WS + kk*KS + woff        (plain k1 / k3 convs)
//  wmode 1: widx = o*1024 + (kk&511)*2 + (kk>>9)  (stride-2 k=2 downsample, K=1024)
//  wmode 2: widx = kk*512 + o                 (codebook [D][NC] as [NC][D])
//  wmode 3: widx = kk*1024 + o*2 + woff       (convT k=2 s=2, w=[I][O][K], torch semantics)
__global__ __launch_bounds__(256) void gemm_k(
    const float* __restrict__ A, const float* __restrict__ W,
    const float* __restrict__ bias, const float* __restrict__ res,
    float* __restrict__ Y, int P, int K, int O,
    int act, int accum, int smod, int shift, int ystride, int yoff,
    int wmode, int WS, int KS, int woff)
{
  __shared__ alignas(16) float As[16][68];
  __shared__ alignas(16) float Bs[16][68];
  const int tid = threadIdx.x;
  const int bp = blockIdx.x * 64, bo = blockIdx.y * 64;
  const int tx = tid & 15, ty = tid >> 4;
  float acc[4][4];
#pragma unroll
  for (int i = 0; i < 4; i++)
#pragma unroll
    for (int j = 0; j < 4; j++) acc[i][j] = 0.f;

  for (int k0 = 0; k0 < K; k0 += 16) {
#pragma unroll
    for (int i = 0; i < 4; i++) {
      const int idx = tid + i * 256;
      const int r = idx >> 4, kc = idx & 15;
      const int p = bp + r;
      const int kk = k0 + kc;
      float v = 0.f;
      bool ok = true;
      if (smod) { const int s = p & (smod - 1); ok = ((unsigned)(s + shift) < (unsigned)smod); }
      if (ok) v = A[(size_t)(p + shift) * K + kk];
      if (act) v = eluf(v);
      As[kc][r] = v;
      const int o = bo + r;
      size_t widx;
      if (wmode == 1)      widx = (size_t)o * 1024 + ((kk & 511) << 1) + (kk >> 9);
      else if (wmode == 2) widx = (size_t)kk * 512 + o;
      else if (wmode == 3) widx = (size_t)kk * 1024 + (o << 1) + woff;
      else                 widx = (size_t)o * WS + (size_t)kk * KS + woff;
      Bs[kc][r] = W[widx];
    }
    __syncthreads();
#pragma unroll
    for (int kk2 = 0; kk2 < 16; kk2++) {
      const float4 av = *(const float4*)&As[kk2][ty * 4];
      const float4 bv = *(const float4*)&Bs[kk2][tx * 4];
      const float a_[4] = {av.x, av.y, av.z, av.w};
      const float b_[4] = {bv.x, bv.y, bv.z, bv.w};
#pragma unroll
      for (int i = 0; i < 4; i++)
#pragma unroll
        for (int j = 0; j < 4; j++) acc[i][j] += a_[i] * b_[j];
    }
    __syncthreads();
  }
#pragma unroll
  for (int i = 0; i < 4; i++) {
    const int p = bp + ty * 4 + i;
    const size_t yrow = (size_t)p * ystride + yoff;
#pragma unroll
    for (int j = 0; j < 4; j++) {
      const int o = bo + tx * 4 + j;
      float v = acc[i][j];
      if (bias) v += bias[o];
      if (res)  v += res[(size_t)p * O + o];
      const size_t yi = yrow * O + o;
      if (accum) v += Y[yi];
      Y[yi] = v;
    }
  }
}

static inline void launch_gemm(hipStream_t st, const float* A, const float* W,
                               const float* bias, const float* res, float* Y,
                               int P, int K, int O, int act, int accum,
                               int smod, int shift, int ystride, int yoff,
                               int wmode, int WS, int KS, int woff)
{
  dim3 g(P / 64, O / 64);
  gemm_k<<<g, 256, 0, st>>>(A, W, bias, res, Y, P, K, O, act, accum, smod, shift,
                            ystride, yoff, wmode, WS, KS, woff);
}

// ---------------- flash attention (fp32); qkv chunk holds batches of S rows (row len 1536)
__global__ __launch_bounds__(256) void attn_k(
    const float* __restrict__ qkv, float* __restrict__ Oa, int S, int base_b)
{
  __shared__ alignas(16) float sq[64][72];
  __shared__ alignas(16) float sk[64][72]; // reused as P tile
  __shared__ alignas(16) float sv[64][72];
  const int tid = threadIdx.x;
  const int bl = blockIdx.y >> 3, h = blockIdx.y & 7;
  const int q0 = blockIdx.x * 64;
  const float* base = qkv + (size_t)bl * S * 1536;
  const int qrow = tid >> 2, jj = tid & 3;

#pragma unroll
  for (int i = 0; i < 16; i++) {
    const int idx = tid + i * 256;
    const int r = idx >> 6, d = idx & 63;
    sq[r][d] = base[(size_t)(q0 + r) * 1536 + h * 64 + d] * 0.125f;
  }
  float acc[16];
#pragma unroll
  for (int i = 0; i < 16; i++) acc[i] = 0.f;
  float m = -INFINITY, l = 0.f;

  for (int t0 = 0; t0 < S; t0 += 64) {
    __syncthreads();
#pragma unroll
    for (int i = 0; i < 16; i++) {
      const int idx = tid + i * 256;
      const int r = idx >> 6, d = idx & 63;
      sk[r][d] = base[(size_t)(t0 + r) * 1536 + 512 + h * 64 + d];
      sv[r][d] = base[(size_t)(t0 + r) * 1536 + 1024 + h * 64 + d];
    }
    __syncthreads();
    float s[16];
#pragma unroll
    for (int t = 0; t < 16; t++) s[t] = 0.f;
#pragma unroll
    for (int d4 = 0; d4 < 16; d4++) {
      const float4 qv = *(const float4*)&sq[qrow][d4 * 4];
#pragma unroll
      for (int t = 0; t < 16; t++) {
        const float4 kv = *(const float4*)&sk[t * 4 + jj][d4 * 4];
        s[t] += qv.x * kv.x + qv.y * kv.y + qv.z * kv.z + qv.w * kv.w;
      }
    }
    float tmax = s[0];
#pragma unroll
    for (int t = 1; t < 16; t++) tmax = fmaxf(tmax, s[t]);
    tmax = fmaxf(tmax, __shfl_xor(tmax, 1));
    tmax = fmaxf(tmax, __shfl_xor(tmax, 2));
    const float newm = fmaxf(m, tmax);
    const float corr = expf(m - newm);
    float psum = 0.f;
#pragma unroll
    for (int t = 0; t < 16; t++) { s[t] = expf(s[t] - newm); psum += s[t]; }
    psum += __shfl_xor(psum, 1);
    psum += __shfl_xor(psum, 2);
    l = l * corr + psum;
    m = newm;
#pragma unroll
    for (int i = 0; i < 16; i++) acc[i] *= corr;
    __syncthreads();
#pragma unroll
    for (int t = 0; t < 16; t++) sk[qrow][t * 4 + jj] = s[t];
    __syncthreads();
#pragma unroll
    for (int kk = 0; kk < 64; kk++) {
      const float pc = sk[qrow][kk];
      const float4 v0 = *(const float4*)&sv[kk][jj * 16 + 0];
      const float4 v1 = *(const float4*)&sv[kk][jj * 16 + 4];
      const float4 v2 = *(const float4*)&sv[kk][jj * 16 + 8];
      const float4 v3 = *(const float4*)&sv[kk][jj * 16 + 12];
      acc[0]  += pc * v0.x; acc[1]  += pc * v0.y; acc[2]  += pc * v0.z; acc[3]  += pc * v0.w;
      acc[4]  += pc * v1.x; acc[5]  += pc * v1.y; acc[6]  += pc * v1.z; acc[7]  += pc * v1.w;
      acc[8]  += pc * v2.x; acc[9]  += pc * v2.y; acc[10] += pc * v2.z; acc[11] += pc * v2.w;
      acc[12] += pc * v3.x; acc[13] += pc * v3.y; acc[14] += pc * v3.z; acc[15] += pc * v3.w;
    }
  }
  const float inv = 1.f / l;
#pragma unroll
  for (int i = 0; i < 16; i++) acc[i] *= inv;
  float4* op = (float4*)&Oa[(size_t)((base_b + bl) * S + q0 + qrow) * 512 + h * 64 + jj * 16];
  op[0] = make_float4(acc[0], acc[1], acc[2], acc[3]);
  op[1] = make_float4(acc[4], acc[5], acc[6], acc[7]);
  op[2] = make_float4(acc[8], acc[9], acc[10], acc[11]);
  op[3] = make_float4(acc[12], acc[13], acc[14], acc[15]);
}

// ---------------- layernorm over C=512, one wave per row
__global__ __launch_bounds__(256) void ln_k(const float* __restrict__ X,
    const float* __restrict__ g, const float* __restrict__ bta,
    float* __restrict__ Y)
{
  const int row = blockIdx.x * 4 + (threadIdx.x >> 6);
  const int lane = threadIdx.x & 63;
  const float* x = X + (size_t)row * 512;
  float v[8]; float s = 0.f;
#pragma unroll
  for (int i = 0; i < 8; i++) { v[i] = x[lane + i * 64]; s += v[i]; }
#pragma unroll
  for (int off = 1; off < 64; off <<= 1) s += __shfl_xor(s, off);
  const float mean = s * (1.f / 512.f);
  float vs = 0.f;
#pragma unroll
  for (int i = 0; i < 8; i++) { const float d = v[i] - mean; vs += d * d; }
#pragma unroll
  for (int off = 1; off < 64; off <<= 1) vs += __shfl_xor(vs, off);
  const float rstd = 1.f / sqrtf(vs * (1.f / 512.f) + 1e-5f);
  float* y = Y + (size_t)row * 512;
#pragma unroll
  for (int i = 0; i < 8; i++) {
    const int c = lane + i * 64;
    y[c] = (v[i] - mean) * rstd * g[c] + bta[c];
  }
}

// ---------------- log_softmax over C=512 -> f32 out
__global__ __launch_bounds__(256) void lsm_k(const float* __restrict__ X,
    float* __restrict__ out)
{
  const int row = blockIdx.x * 4 + (threadIdx.x >> 6);
  const int lane = threadIdx.x & 63;
  const float* x = X + (size_t)row * 512;
  float v[8]; float mx = -3.0e38f;
#pragma unroll
  for (int i = 0; i < 8; i++) { v[i] = x[lane + i * 64]; mx = fmaxf(mx, v[i]); }
#pragma unroll
  for (int off = 1; off < 64; off <<= 1) mx = fmaxf(mx, __shfl_xor(mx, off));
  float sum = 0.f;
#pragma unroll
  for (int i = 0; i < 8; i++) sum += expf(v[i] - mx);
#pragma unroll
  for (int off = 1; off < 64; off <<= 1) sum += __shfl_xor(sum, off);
  const float ls = logf(sum);
  float* y = out + (size_t)row * 512;
#pragma unroll
  for (int i = 0; i < 8; i++) y[lane + i * 64] = v[i] - mx - ls;
}

// ---------------- embedding gather
__global__ __launch_bounds__(256) void embed_k(const int* __restrict__ x,
    const float* __restrict__ emb, float* __restrict__ out)
{
  const int i = blockIdx.x * 256 + threadIdx.x; // 8192*128 float4s
  const int p = i >> 7, c4 = i & 127;
  const int id = x[p];
  *(float4*)&out[(size_t)p * 512 + c4 * 4] = *(const float4*)&emb[(size_t)id * 512 + c4 * 4];
}

// ---------------- codebook column norms (codebook is [D][NC])
__global__ __launch_bounds__(64) void cnorm_k(const float* __restrict__ cb, float* __restrict__ cn)
{
  const int n = blockIdx.x; const int lane = threadIdx.x;
  float s = 0.f;
#pragma unroll
  for (int i = 0; i < 8; i++) {
    const float v = cb[(size_t)(lane + i * 64) * 512 + n];
    s += v * v;
  }
#pragma unroll
  for (int off = 1; off < 64; off <<= 1) s += __shfl_xor(s, off);
  if (lane == 0) cn[n] = s;
}

// ---------------- VQ argmin (dist = |c|^2 - 2 z.c + const)
__global__ __launch_bounds__(256) void argmin_k(const float* __restrict__ scores,
    const float* __restrict__ cn, int* __restrict__ ids,
    float* __restrict__ out_ids)
{
  const int row = blockIdx.x * 4 + (threadIdx.x >> 6);
  const int lane = threadIdx.x & 63;
  const float* sr = scores + (size_t)row * 512;
  float best = 3.0e38f; int bi = 0x7fffffff;
#pragma unroll
  for (int i = 0; i < 8; i++) {
    const int n = lane + i * 64;
    const float v = cn[n] - 2.f * sr[n];
    if (v < best || (v == best && n < bi)) { best = v; bi = n; }
  }
#pragma unroll
  for (int off = 1; off < 64; off <<= 1) {
    const float ov = __shfl_xor(best, off);
    const int oi = __shfl_xor(bi, off);
    if (ov < best || (ov == best && oi < bi)) { best = ov; bi = oi; }
  }
  if (lane == 0) { ids[row] = bi; out_ids[row] = (float)bi; }
}

// ---------------- z = z_e + (q - z_e) -> f32 out_z (decoder reads it too); diff partials
__global__ __launch_bounds__(128) void zq_k(const float* __restrict__ z_e,
    const float* __restrict__ cb, const int* __restrict__ ids,
    float* __restrict__ zout, float* __restrict__ dpart)
{
  __shared__ float red[2];
  const int p = blockIdx.x, t = threadIdx.x;
  const int id = ids[p];
  const float4 ze = *(const float4*)&z_e[(size_t)p * 512 + t * 4];
  const float q0 = cb[(size_t)(t * 4 + 0) * 512 + id];
  const float q1 = cb[(size_t)(t * 4 + 1) * 512 + id];
  const float q2 = cb[(size_t)(t * 4 + 2) * 512 + id];
  const float q3 = cb[(size_t)(t * 4 + 3) * 512 + id];
  const float4 dv = make_float4(q0 - ze.x, q1 - ze.y, q2 - ze.z, q3 - ze.w);
  *(float4*)&zout[(size_t)p * 512 + t * 4] = make_float4(q0, q1, q2, q3); // z_e + (q - z_e) == q numerically? NO: keep exact form
  // NOTE: straight-through z = z_e + (q - z_e) is exactly q in fp arithmetic only if
  // computed as written; jax computes z_e + (q - z_e) which may differ by rounding.
  // Use the literal form to match:
  {
    const float4 z = make_float4(ze.x + dv.x, ze.y + dv.y, ze.z + dv.z, ze.w + dv.w);
    *(float4*)&zout[(size_t)p * 512 + t * 4] = z;
  }
  float loc = dv.x * dv.x + dv.y * dv.y + dv.z * dv.z + dv.w * dv.w;
#pragma unroll
  for (int off = 1; off < 64; off <<= 1) loc += __shfl_xor(loc, off);
  const int lane = t & 63, w = t >> 6;
  if (lane == 0) red[w] = loc;
  __syncthreads();
  if (t == 0) dpart[p] = red[0] + red[1];
}

__global__ __launch_bounds__(256) void diffred_k(const float* __restrict__ dpart,
    float* __restrict__ out_diff)
{
  __shared__ float red[4];
  const int t = threadIdx.x;
  float s = 0.f;
#pragma unroll
  for (int i = 0; i < 8; i++) s += dpart[t + i * 256];
#pragma unroll
  for (int off = 1; off < 64; off <<= 1) s += __shfl_xor(s, off);
  if ((t & 63) == 0) red[t >> 6] = s;
  __syncthreads();
  if (t == 0) out_diff[0] = (red[0] + red[1] + red[2] + red[3]) * (1.f / 1048576.f);
}

// =====================================================================
extern "C" void kernel_launch(void* const* d_in, const int* in_sizes, int n_in,
                              void* d_out, int out_size, void* d_ws, size_t ws_size,
                              hipStream_t stream)
{
  const int*   x         = (const int*)d_in[0];
  const float* embed     = (const float*)d_in[1];
  const float* enc_res_w = (const float*)d_in[2];
  const float* enc_res_b = (const float*)d_in[3];
  const float* enc_in_w  = (const float*)d_in[4];
  const float* enc_in_b  = (const float*)d_in[5];
  const float* enc_out_w = (const float*)d_in[6];
  const float* enc_out_b = (const float*)d_in[7];
  const float* enc_ln_g  = (const float*)d_in[8];
  const float* enc_ln_b  = (const float*)d_in[9];
  const float* enc_down_w= (const float*)d_in[10];
  const float* enc_down_b= (const float*)d_in[11];
  const float* e2q_w     = (const float*)d_in[12];
  const float* e2q_b     = (const float*)d_in[13];
  const float* codebook  = (const float*)d_in[14];
  const float* q2d_w     = (const float*)d_in[15];
  const float* q2d_b     = (const float*)d_in[16];
  const float* dec_res_w = (const float*)d_in[17];
  const float* dec_res_b = (const float*)d_in[18];
  const float* dec_in_w  = (const float*)d_in[19];
  const float* dec_in_b  = (const float*)d_in[20];
  const float* dec_out_w = (const float*)d_in[21];
  const float* dec_out_b = (const float*)d_in[22];
  const float* dec_ln_g  = (const float*)d_in[23];
  const float* dec_ln_b  = (const float*)d_in[24];
  const float* dec_up_w  = (const float*)d_in[25];
  const float* dec_up_b  = (const float*)d_in[26];

  float* ws = (float*)d_ws;
  float* S0   = ws;
  float* S1   = ws + SLOT;
  float* S2   = ws + 2 * SLOT;
  float* QKVb = ws + 3 * SLOT;               // 1024*1536 floats
  float* cnorm = QKVb + 1572864;             // [512]
  int*   idsI  = (int*)(cnorm + 512);        // [2048]
  float* dpart = (float*)(idsI + 2048);      // [2048]

  float* out      = (float*)d_out;           // FLOAT32 output buffer
  float* out_logp = out;                     // 4194304
  float* out_z    = out + 4194304;           // 1048576
  float* out_diff = out + 5242880;           // 1
  float* out_ids  = out + 5242881;           // 2048

  cnorm_k<<<512, 64, 0, stream>>>(codebook, cnorm);

  // ---- encoder ----
  embed_k<<<4096, 256, 0, stream>>>(x, embed, S0);
  launch_gemm(stream, S0, enc_res_w,          enc_res_b,        nullptr, S1, 8192, 512, 512, 1, 0, 0, 0, 1, 0, 0, 512, 1, 0);
  launch_gemm(stream, S1, enc_res_w + 262144, enc_res_b + 512,  nullptr, S2, 8192, 512, 512, 1, 0, 0, 0, 1, 0, 0, 512, 1, 0);
  launch_gemm(stream, S2, enc_res_w + 524288, enc_res_b + 1024, S0,      S1, 8192, 512, 512, 1, 0, 0, 0, 1, 0, 0, 512, 1, 0);
  for (int b = 0; b < 8; b++) {
    launch_gemm(stream, S1 + (size_t)b * 1024 * 512, enc_in_w, enc_in_b, nullptr, QKVb,
                1024, 512, 1536, 0, 0, 0, 0, 1, 0, 0, 512, 1, 0);
    attn_k<<<dim3(16, 8), 256, 0, stream>>>(QKVb, S2, 1024, b);
  }
  launch_gemm(stream, S2, enc_out_w, enc_out_b, S1, S0, 8192, 512, 512, 0, 0, 0, 0, 1, 0, 0, 512, 1, 0);
  ln_k<<<2048, 256, 0, stream>>>(S0, enc_ln_g, enc_ln_b, S1);
  launch_gemm(stream, S1, enc_down_w,          enc_down_b,       nullptr, S2, 4096, 1024, 512, 0, 0, 0, 0, 1, 0, 1, 0, 0, 0);
  launch_gemm(stream, S2, enc_down_w + 524288, enc_down_b + 512, nullptr, S0, 2048, 1024, 512, 0, 0, 0, 0, 1, 0, 1, 0, 0, 0);
  launch_gemm(stream, S0, e2q_w, e2q_b,   nullptr, S2, 2048, 512, 512, 0, 0, 256, -1, 1, 0, 0, 1536, 3, 0);
  launch_gemm(stream, S0, e2q_w, nullptr, nullptr, S2, 2048, 512, 512, 0, 1, 256,  0, 1, 0, 0, 1536, 3, 1);
  launch_gemm(stream, S0, e2q_w, nullptr, nullptr, S2, 2048, 512, 512, 0, 1, 256,  1, 1, 0, 0, 1536, 3, 2);
  // ---- VQ ----
  launch_gemm(stream, S2, codebook, nullptr, nullptr, S1, 2048, 512, 512, 0, 0, 0, 0, 1, 0, 2, 0, 0, 0);
  argmin_k<<<512, 256, 0, stream>>>(S1, cnorm, idsI, out_ids);
  zq_k<<<2048, 128, 0, stream>>>(S2, codebook, idsI, out_z, dpart);
  diffred_k<<<1, 256, 0, stream>>>(dpart, out_diff);
  // ---- decoder (reads z from out_z) ----
  launch_gemm(stream, out_z, q2d_w, q2d_b,   nullptr, S1, 2048, 512, 512, 0, 0, 256, -1, 1, 0, 0, 1536, 3, 0);
  launch_gemm(stream, out_z, q2d_w, nullptr, nullptr, S1, 2048, 512, 512, 0, 1, 256,  0, 1, 0, 0, 1536, 3, 1);
  launch_gemm(stream, out_z, q2d_w, nullptr, nullptr, S1, 2048, 512, 512, 0, 1, 256,  1, 1, 0, 0, 1536, 3, 2);
  // dec block 0 (P=2048, S=256)
  launch_gemm(stream, S1, dec_res_w,          dec_res_b,        nullptr, S2, 2048, 512, 512, 1, 0, 0, 0, 1, 0, 0, 512, 1, 0);
  launch_gemm(stream, S2, dec_res_w + 262144, dec_res_b + 512,  nullptr, S0, 2048, 512, 512, 1, 0, 0, 0, 1, 0, 0, 512, 1, 0);
  launch_gemm(stream, S0, dec_res_w + 524288, dec_res_b + 1024, S1,      S2, 2048, 512, 512, 1, 0, 0, 0, 1, 0, 0, 512, 1, 0);
  for (int it = 0; it < 2; it++) {
    launch_gemm(stream, S2 + (size_t)it * 1024 * 512, dec_in_w, dec_in_b, nullptr, QKVb,
                1024, 512, 1536, 0, 0, 0, 0, 1, 0, 0, 512, 1, 0);
    attn_k<<<dim3(4, 32), 256, 0, stream>>>(QKVb, S0, 256, it * 4);
  }
  launch_gemm(stream, S0, dec_out_w, dec_out_b, S2, S1, 2048, 512, 512, 0, 0, 0, 0, 1, 0, 0, 512, 1, 0);
  ln_k<<<512, 256, 0, stream>>>(S1, dec_ln_g, dec_ln_b, S2);
  launch_gemm(stream, S2, dec_up_w, dec_up_b, nullptr, S0, 2048, 512, 512, 0, 0, 0, 0, 2, 0, 3, 0, 0, 0);
  launch_gemm(stream, S2, dec_up_w, dec_up_b, nullptr, S0, 2048, 512, 512, 0, 0, 0, 0, 2, 1, 3, 0, 0, 1);
  // dec block 1 (P=4096, S=512)
  launch_gemm(stream, S0, dec_res_w + 786432,  dec_res_b + 1536, nullptr, S1, 4096, 512, 512, 1, 0, 0, 0, 1, 0, 0, 512, 1, 0);
  launch_gemm(stream, S1, dec_res_w + 1048576, dec_res_b + 2048, nullptr, S2, 4096, 512, 512, 1, 0, 0, 0, 1, 0, 0, 512, 1, 0);
  launch_gemm(stream, S2, dec_res_w + 1310720, dec_res_b + 2560, S0,      S1, 4096, 512, 512, 1, 0, 0, 0, 1, 0, 0, 512, 1, 0);
  for (int it = 0; it < 4; it++) {
    launch_gemm(stream, S1 + (size_t)it * 1024 * 512, dec_in_w + 786432, dec_in_b + 1536, nullptr, QKVb,
                1024, 512, 1536, 0, 0, 0, 0, 1, 0, 0, 512, 1, 0);
    attn_k<<<dim3(8, 16), 256, 0, stream>>>(QKVb, S2, 512, it * 2);
  }
  launch_gemm(stream, S2, dec_out_w + 262144, dec_out_b + 512, S1, S0, 4096, 512, 512, 0, 0, 0, 0, 1, 0, 0, 512, 1, 0);
  ln_k<<<1024, 256, 0, stream>>>(S0, dec_ln_g + 512, dec_ln_b + 512, S1);
  launch_gemm(stream, S1, dec_up_w + 524288, dec_up_b + 512, nullptr, S0, 4096, 512, 512, 0, 0, 0, 0, 2, 0, 3, 0, 0, 0);
  launch_gemm(stream, S1, dec_up_w + 524288, dec_up_b + 512, nullptr, S0, 4096, 512, 512, 0, 0, 0, 0, 2, 1, 3, 0, 0, 1);
  // ---- log_softmax -> f32 out ----
  lsm_k<<<2048, 256, 0, stream>>>(S0, out_logp);
}

// Round 4
// 3885.851 us; speedup vs baseline: 1.6935x; 1.6935x over previous
//
#include <hip/hip_runtime.h>
#include <hip/hip_bf16.h>

// B=8 S=1024 C=512 V=512 D=512 NC=512 NF=2 H=8 TAU=1
// d_out is FLOAT32: [logp 4194304][z 1048576][diff 1][ids 2048]
// ws (full path): S0,S1,S2 (8192x512 f32) + QKV (8192x1536) + tail ≈ 100.7 MB.
// Fallback (small ws): QKV chunk of 1024x1536, per-batch attention launches.

static constexpr size_t SLOT = 4194304; // 8192*512 floats

__device__ __forceinline__ float eluf(float x) { return x > 0.f ? x : expm1f(x); }

// Weight index modes:
//  wmode 0: widx = o*WS + kk*KS + woff        (plain k1 / k3 convs)
//  wmode 1: widx = o*1024 + (kk&511)*2 + (kk>>9)  (stride-2 k=2 downsample, K=1024)
//  wmode 2: widx = kk*512 + o                 (codebook [D][NC] as [NC][D])
//  wmode 3: widx = kk*1024 + o*2 + woff       (convT k=2 s=2, w=[I][O][K], torch semantics)
__global__ __launch_bounds__(256) void gemm_k(
    const float* __restrict__ A, const float* __restrict__ W,
    const float* __restrict__ bias, const float* __restrict__ res,
    float* __restrict__ Y, int P, int K, int O,
    int act, int accum, int smod, int shift, int ystride, int yoff,
    int wmode, int WS, int KS, int woff)
{
  __shared__ alignas(16) float As[16][68];
  __shared__ alignas(16) float Bs[16][68];
  const int tid = threadIdx.x;
  const int bp = blockIdx.x * 64, bo = blockIdx.y * 64;
  const int tx = tid & 15, ty = tid >> 4;
  float acc[4][4];
#pragma unroll
  for (int i = 0; i < 4; i++)
#pragma unroll
    for (int j = 0; j < 4; j++) acc[i][j] = 0.f;

  for (int k0 = 0; k0 < K; k0 += 16) {
#pragma unroll
    for (int i = 0; i < 4; i++) {
      const int idx = tid + i * 256;
      const int r = idx >> 4, kc = idx & 15;
      const int p = bp + r;
      const int kk = k0 + kc;
      float v = 0.f;
      bool ok = true;
      if (smod) { const int s = p & (smod - 1); ok = ((unsigned)(s + shift) < (unsigned)smod); }
      if (ok) v = A[(size_t)(p + shift) * K + kk];
      if (act) v = eluf(v);
      As[kc][r] = v;
      const int o = bo + r;
      size_t widx;
      if (wmode == 1)      widx = (size_t)o * 1024 + ((kk & 511) << 1) + (kk >> 9);
      else if (wmode == 2) widx = (size_t)kk * 512 + o;
      else if (wmode == 3) widx = (size_t)kk * 1024 + (o << 1) + woff;
      else                 widx = (size_t)o * WS + (size_t)kk * KS + woff;
      Bs[kc][r] = W[widx];
    }
    __syncthreads();
#pragma unroll
    for (int kk2 = 0; kk2 < 16; kk2++) {
      const float4 av = *(const float4*)&As[kk2][ty * 4];
      const float4 bv = *(const float4*)&Bs[kk2][tx * 4];
      const float a_[4] = {av.x, av.y, av.z, av.w};
      const float b_[4] = {bv.x, bv.y, bv.z, bv.w};
#pragma unroll
      for (int i = 0; i < 4; i++)
#pragma unroll
        for (int j = 0; j < 4; j++) acc[i][j] += a_[i] * b_[j];
    }
    __syncthreads();
  }
#pragma unroll
  for (int i = 0; i < 4; i++) {
    const int p = bp + ty * 4 + i;
    const size_t yrow = (size_t)p * ystride + yoff;
#pragma unroll
    for (int j = 0; j < 4; j++) {
      const int o = bo + tx * 4 + j;
      float v = acc[i][j];
      if (bias) v += bias[o];
      if (res)  v += res[(size_t)p * O + o];
      const size_t yi = yrow * O + o;
      if (accum) v += Y[yi];
      Y[yi] = v;
    }
  }
}

static inline void launch_gemm(hipStream_t st, const float* A, const float* W,
                               const float* bias, const float* res, float* Y,
                               int P, int K, int O, int act, int accum,
                               int smod, int shift, int ystride, int yoff,
                               int wmode, int WS, int KS, int woff)
{
  dim3 g(P / 64, O / 64);
  gemm_k<<<g, 256, 0, st>>>(A, W, bias, res, Y, P, K, O, act, accum, smod, shift,
                            ystride, yoff, wmode, WS, KS, woff);
}

// ---------------- flash attention (fp32); grid = (S/64, nb*8); qkv rows of 1536
__global__ __launch_bounds__(256) void attn_k(
    const float* __restrict__ qkv, float* __restrict__ Oa, int S, int base_b)
{
  __shared__ alignas(16) float sq[64][68];
  __shared__ alignas(16) float sk[64][68]; // reused as P tile
  __shared__ alignas(16) float sv[64][68];
  const int tid = threadIdx.x;
  const int bl = blockIdx.y >> 3, h = blockIdx.y & 7;
  const int q0 = blockIdx.x * 64;
  const float* base = qkv + (size_t)bl * S * 1536;
  const int qrow = tid >> 2, jj = tid & 3;

#pragma unroll
  for (int i = 0; i < 16; i++) {
    const int idx = tid + i * 256;
    const int r = idx >> 6, d = idx & 63;
    sq[r][d] = base[(size_t)(q0 + r) * 1536 + h * 64 + d] * 0.125f;
  }
  float acc[16];
#pragma unroll
  for (int i = 0; i < 16; i++) acc[i] = 0.f;
  float m = -INFINITY, l = 0.f;

  for (int t0 = 0; t0 < S; t0 += 64) {
    __syncthreads();
#pragma unroll
    for (int i = 0; i < 16; i++) {
      const int idx = tid + i * 256;
      const int r = idx >> 6, d = idx & 63;
      sk[r][d] = base[(size_t)(t0 + r) * 1536 + 512 + h * 64 + d];
      sv[r][d] = base[(size_t)(t0 + r) * 1536 + 1024 + h * 64 + d];
    }
    __syncthreads();
    float s[16];
#pragma unroll
    for (int t = 0; t < 16; t++) s[t] = 0.f;
#pragma unroll
    for (int d4 = 0; d4 < 16; d4++) {
      const float4 qv = *(const float4*)&sq[qrow][d4 * 4];
#pragma unroll
      for (int t = 0; t < 16; t++) {
        const float4 kv = *(const float4*)&sk[t * 4 + jj][d4 * 4];
        s[t] += qv.x * kv.x + qv.y * kv.y + qv.z * kv.z + qv.w * kv.w;
      }
    }
    float tmax = s[0];
#pragma unroll
    for (int t = 1; t < 16; t++) tmax = fmaxf(tmax, s[t]);
    tmax = fmaxf(tmax, __shfl_xor(tmax, 1));
    tmax = fmaxf(tmax, __shfl_xor(tmax, 2));
    const float newm = fmaxf(m, tmax);
    const float corr = expf(m - newm);
    float psum = 0.f;
#pragma unroll
    for (int t = 0; t < 16; t++) { s[t] = expf(s[t] - newm); psum += s[t]; }
    psum += __shfl_xor(psum, 1);
    psum += __shfl_xor(psum, 2);
    l = l * corr + psum;
    m = newm;
#pragma unroll
    for (int i = 0; i < 16; i++) acc[i] *= corr;
    __syncthreads();
#pragma unroll
    for (int t = 0; t < 16; t++) sk[qrow][t * 4 + jj] = s[t];
    __syncthreads();
#pragma unroll
    for (int kk = 0; kk < 64; kk++) {
      const float pc = sk[qrow][kk];
      const float4 v0 = *(const float4*)&sv[kk][jj * 16 + 0];
      const float4 v1 = *(const float4*)&sv[kk][jj * 16 + 4];
      const float4 v2 = *(const float4*)&sv[kk][jj * 16 + 8];
      const float4 v3 = *(const float4*)&sv[kk][jj * 16 + 12];
      acc[0]  += pc * v0.x; acc[1]  += pc * v0.y; acc[2]  += pc * v0.z; acc[3]  += pc * v0.w;
      acc[4]  += pc * v1.x; acc[5]  += pc * v1.y; acc[6]  += pc * v1.z; acc[7]  += pc * v1.w;
      acc[8]  += pc * v2.x; acc[9]  += pc * v2.y; acc[10] += pc * v2.z; acc[11] += pc * v2.w;
      acc[12] += pc * v3.x; acc[13] += pc * v3.y; acc[14] += pc * v3.z; acc[15] += pc * v3.w;
    }
  }
  const float inv = 1.f / l;
#pragma unroll
  for (int i = 0; i < 16; i++) acc[i] *= inv;
  float4* op = (float4*)&Oa[(size_t)((base_b + bl) * S + q0 + qrow) * 512 + h * 64 + jj * 16];
  op[0] = make_float4(acc[0], acc[1], acc[2], acc[3]);
  op[1] = make_float4(acc[4], acc[5], acc[6], acc[7]);
  op[2] = make_float4(acc[8], acc[9], acc[10], acc[11]);
  op[3] = make_float4(acc[12], acc[13], acc[14], acc[15]);
}

// ---------------- layernorm over C=512, one wave per row
__global__ __launch_bounds__(256) void ln_k(const float* __restrict__ X,
    const float* __restrict__ g, const float* __restrict__ bta,
    float* __restrict__ Y)
{
  const int row = blockIdx.x * 4 + (threadIdx.x >> 6);
  const int lane = threadIdx.x & 63;
  const float* x = X + (size_t)row * 512;
  float v[8]; float s = 0.f;
#pragma unroll
  for (int i = 0; i < 8; i++) { v[i] = x[lane + i * 64]; s += v[i]; }
#pragma unroll
  for (int off = 1; off < 64; off <<= 1) s += __shfl_xor(s, off);
  const float mean = s * (1.f / 512.f);
  float vs = 0.f;
#pragma unroll
  for (int i = 0; i < 8; i++) { const float d = v[i] - mean; vs += d * d; }
#pragma unroll
  for (int off = 1; off < 64; off <<= 1) vs += __shfl_xor(vs, off);
  const float rstd = 1.f / sqrtf(vs * (1.f / 512.f) + 1e-5f);
  float* y = Y + (size_t)row * 512;
#pragma unroll
  for (int i = 0; i < 8; i++) {
    const int c = lane + i * 64;
    y[c] = (v[i] - mean) * rstd * g[c] + bta[c];
  }
}

// ---------------- log_softmax over C=512 -> f32 out
__global__ __launch_bounds__(256) void lsm_k(const float* __restrict__ X,
    float* __restrict__ out)
{
  const int row = blockIdx.x * 4 + (threadIdx.x >> 6);
  const int lane = threadIdx.x & 63;
  const float* x = X + (size_t)row * 512;
  float v[8]; float mx = -3.0e38f;
#pragma unroll
  for (int i = 0; i < 8; i++) { v[i] = x[lane + i * 64]; mx = fmaxf(mx, v[i]); }
#pragma unroll
  for (int off = 1; off < 64; off <<= 1) mx = fmaxf(mx, __shfl_xor(mx, off));
  float sum = 0.f;
#pragma unroll
  for (int i = 0; i < 8; i++) sum += expf(v[i] - mx);
#pragma unroll
  for (int off = 1; off < 64; off <<= 1) sum += __shfl_xor(sum, off);
  const float ls = logf(sum);
  float* y = out + (size_t)row * 512;
#pragma unroll
  for (int i = 0; i < 8; i++) y[lane + i * 64] = v[i] - mx - ls;
}

// ---------------- embedding gather
__global__ __launch_bounds__(256) void embed_k(const int* __restrict__ x,
    const float* __restrict__ emb, float* __restrict__ out)
{
  const int i = blockIdx.x * 256 + threadIdx.x; // 8192*128 float4s
  const int p = i >> 7, c4 = i & 127;
  const int id = x[p];
  *(float4*)&out[(size_t)p * 512 + c4 * 4] = *(const float4*)&emb[(size_t)id * 512 + c4 * 4];
}

// ---------------- codebook column norms (codebook is [D][NC])
__global__ __launch_bounds__(64) void cnorm_k(const float* __restrict__ cb, float* __restrict__ cn)
{
  const int n = blockIdx.x; const int lane = threadIdx.x;
  float s = 0.f;
#pragma unroll
  for (int i = 0; i < 8; i++) {
    const float v = cb[(size_t)(lane + i * 64) * 512 + n];
    s += v * v;
  }
#pragma unroll
  for (int off = 1; off < 64; off <<= 1) s += __shfl_xor(s, off);
  if (lane == 0) cn[n] = s;
}

// ---------------- VQ argmin (dist = |c|^2 - 2 z.c + const)
__global__ __launch_bounds__(256) void argmin_k(const float* __restrict__ scores,
    const float* __restrict__ cn, int* __restrict__ ids,
    float* __restrict__ out_ids)
{
  const int row = blockIdx.x * 4 + (threadIdx.x >> 6);
  const int lane = threadIdx.x & 63;
  const float* sr = scores + (size_t)row * 512;
  float best = 3.0e38f; int bi = 0x7fffffff;
#pragma unroll
  for (int i = 0; i < 8; i++) {
    const int n = lane + i * 64;
    const float v = cn[n] - 2.f * sr[n];
    if (v < best || (v == best && n < bi)) { best = v; bi = n; }
  }
#pragma unroll
  for (int off = 1; off < 64; off <<= 1) {
    const float ov = __shfl_xor(best, off);
    const int oi = __shfl_xor(bi, off);
    if (ov < best || (ov == best && oi < bi)) { best = ov; bi = oi; }
  }
  if (lane == 0) { ids[row] = bi; out_ids[row] = (float)bi; }
}

// ---------------- z = z_e + (q - z_e) -> f32 out_z; diff partials
__global__ __launch_bounds__(128) void zq_k(const float* __restrict__ z_e,
    const float* __restrict__ cb, const int* __restrict__ ids,
    float* __restrict__ zout, float* __restrict__ dpart)
{
  __shared__ float red[2];
  const int p = blockIdx.x, t = threadIdx.x;
  const int id = ids[p];
  const float4 ze = *(const float4*)&z_e[(size_t)p * 512 + t * 4];
  const float q0 = cb[(size_t)(t * 4 + 0) * 512 + id];
  const float q1 = cb[(size_t)(t * 4 + 1) * 512 + id];
  const float q2 = cb[(size_t)(t * 4 + 2) * 512 + id];
  const float q3 = cb[(size_t)(t * 4 + 3) * 512 + id];
  const float4 dv = make_float4(q0 - ze.x, q1 - ze.y, q2 - ze.z, q3 - ze.w);
  const float4 z  = make_float4(ze.x + dv.x, ze.y + dv.y, ze.z + dv.z, ze.w + dv.w);
  *(float4*)&zout[(size_t)p * 512 + t * 4] = z;
  float loc = dv.x * dv.x + dv.y * dv.y + dv.z * dv.z + dv.w * dv.w;
#pragma unroll
  for (int off = 1; off < 64; off <<= 1) loc += __shfl_xor(loc, off);
  const int lane = t & 63, w = t >> 6;
  if (lane == 0) red[w] = loc;
  __syncthreads();
  if (t == 0) dpart[p] = red[0] + red[1];
}

__global__ __launch_bounds__(256) void diffred_k(const float* __restrict__ dpart,
    float* __restrict__ out_diff)
{
  __shared__ float red[4];
  const int t = threadIdx.x;
  float s = 0.f;
#pragma unroll
  for (int i = 0; i < 8; i++) s += dpart[t + i * 256];
#pragma unroll
  for (int off = 1; off < 64; off <<= 1) s += __shfl_xor(s, off);
  if ((t & 63) == 0) red[t >> 6] = s;
  __syncthreads();
  if (t == 0) out_diff[0] = (red[0] + red[1] + red[2] + red[3]) * (1.f / 1048576.f);
}

// =====================================================================
extern "C" void kernel_launch(void* const* d_in, const int* in_sizes, int n_in,
                              void* d_out, int out_size, void* d_ws, size_t ws_size,
                              hipStream_t stream)
{
  const int*   x         = (const int*)d_in[0];
  const float* embed     = (const float*)d_in[1];
  const float* enc_res_w = (const float*)d_in[2];
  const float* enc_res_b = (const float*)d_in[3];
  const float* enc_in_w  = (const float*)d_in[4];
  const float* enc_in_b  = (const float*)d_in[5];
  const float* enc_out_w = (const float*)d_in[6];
  const float* enc_out_b = (const float*)d_in[7];
  const float* enc_ln_g  = (const float*)d_in[8];
  const float* enc_ln_b  = (const float*)d_in[9];
  const float* enc_down_w= (const float*)d_in[10];
  const float* enc_down_b= (const float*)d_in[11];
  const float* e2q_w     = (const float*)d_in[12];
  const float* e2q_b     = (const float*)d_in[13];
  const float* codebook  = (const float*)d_in[14];
  const float* q2d_w     = (const float*)d_in[15];
  const float* q2d_b     = (const float*)d_in[16];
  const float* dec_res_w = (const float*)d_in[17];
  const float* dec_res_b = (const float*)d_in[18];
  const float* dec_in_w  = (const float*)d_in[19];
  const float* dec_in_b  = (const float*)d_in[20];
  const float* dec_out_w = (const float*)d_in[21];
  const float* dec_out_b = (const float*)d_in[22];
  const float* dec_ln_g  = (const float*)d_in[23];
  const float* dec_ln_b  = (const float*)d_in[24];
  const float* dec_up_w  = (const float*)d_in[25];
  const float* dec_up_b  = (const float*)d_in[26];

  float* ws = (float*)d_ws;
  float* S0   = ws;
  float* S1   = ws + SLOT;
  float* S2   = ws + 2 * SLOT;
  float* QKVb = ws + 3 * SLOT;               // full: 8192*1536; fallback: 1024*1536

  const size_t fullQKV = (size_t)8192 * 1536;
  const size_t needed_full = ((size_t)3 * SLOT + fullQKV + 8192) * 4;
  const bool full = ws_size >= needed_full;
  const size_t qkvlen = full ? fullQKV : (size_t)1024 * 1536;

  float* cnorm = QKVb + qkvlen;              // [512]
  int*   idsI  = (int*)(cnorm + 512);        // [2048]
  float* dpart = (float*)(idsI + 2048);      // [2048]

  float* out      = (float*)d_out;           // FLOAT32 output buffer
  float* out_logp = out;                     // 4194304
  float* out_z    = out + 4194304;           // 1048576
  float* out_diff = out + 5242880;           // 1
  float* out_ids  = out + 5242881;           // 2048

  cnorm_k<<<512, 64, 0, stream>>>(codebook, cnorm);

  // ---- encoder ----
  embed_k<<<4096, 256, 0, stream>>>(x, embed, S0);
  launch_gemm(stream, S0, enc_res_w,          enc_res_b,        nullptr, S1, 8192, 512, 512, 1, 0, 0, 0, 1, 0, 0, 512, 1, 0);
  launch_gemm(stream, S1, enc_res_w + 262144, enc_res_b + 512,  nullptr, S2, 8192, 512, 512, 1, 0, 0, 0, 1, 0, 0, 512, 1, 0);
  launch_gemm(stream, S2, enc_res_w + 524288, enc_res_b + 1024, S0,      S1, 8192, 512, 512, 1, 0, 0, 0, 1, 0, 0, 512, 1, 0);
  if (full) {
    launch_gemm(stream, S1, enc_in_w, enc_in_b, nullptr, QKVb, 8192, 512, 1536, 0, 0, 0, 0, 1, 0, 0, 512, 1, 0);
    attn_k<<<dim3(16, 64), 256, 0, stream>>>(QKVb, S2, 1024, 0);
  } else {
    for (int b = 0; b < 8; b++) {
      launch_gemm(stream, S1 + (size_t)b * 1024 * 512, enc_in_w, enc_in_b, nullptr, QKVb,
                  1024, 512, 1536, 0, 0, 0, 0, 1, 0, 0, 512, 1, 0);
      attn_k<<<dim3(16, 8), 256, 0, stream>>>(QKVb, S2, 1024, b);
    }
  }
  launch_gemm(stream, S2, enc_out_w, enc_out_b, S1, S0, 8192, 512, 512, 0, 0, 0, 0, 1, 0, 0, 512, 1, 0);
  ln_k<<<2048, 256, 0, stream>>>(S0, enc_ln_g, enc_ln_b, S1);
  launch_gemm(stream, S1, enc_down_w,          enc_down_b,       nullptr, S2, 4096, 1024, 512, 0, 0, 0, 0, 1, 0, 1, 0, 0, 0);
  launch_gemm(stream, S2, enc_down_w + 524288, enc_down_b + 512, nullptr, S0, 2048, 1024, 512, 0, 0, 0, 0, 1, 0, 1, 0, 0, 0);
  launch_gemm(stream, S0, e2q_w, e2q_b,   nullptr, S2, 2048, 512, 512, 0, 0, 256, -1, 1, 0, 0, 1536, 3, 0);
  launch_gemm(stream, S0, e2q_w, nullptr, nullptr, S2, 2048, 512, 512, 0, 1, 256,  0, 1, 0, 0, 1536, 3, 1);
  launch_gemm(stream, S0, e2q_w, nullptr, nullptr, S2, 2048, 512, 512, 0, 1, 256,  1, 1, 0, 0, 1536, 3, 2);
  // ---- VQ ----
  launch_gemm(stream, S2, codebook, nullptr, nullptr, S1, 2048, 512, 512, 0, 0, 0, 0, 1, 0, 2, 0, 0, 0);
  argmin_k<<<512, 256, 0, stream>>>(S1, cnorm, idsI, out_ids);
  zq_k<<<2048, 128, 0, stream>>>(S2, codebook, idsI, out_z, dpart);
  diffred_k<<<1, 256, 0, stream>>>(dpart, out_diff);
  // ---- decoder (reads z from out_z) ----
  launch_gemm(stream, out_z, q2d_w, q2d_b,   nullptr, S1, 2048, 512, 512, 0, 0, 256, -1, 1, 0, 0, 1536, 3, 0);
  launch_gemm(stream, out_z, q2d_w, nullptr, nullptr, S1, 2048, 512, 512, 0, 1, 256,  0, 1, 0, 0, 1536, 3, 1);
  launch_gemm(stream, out_z, q2d_w, nullptr, nullptr, S1, 2048, 512, 512, 0, 1, 256,  1, 1, 0, 0, 1536, 3, 2);
  // dec block 0 (P=2048, S=256)
  launch_gemm(stream, S1, dec_res_w,          dec_res_b,        nullptr, S2, 2048, 512, 512, 1, 0, 0, 0, 1, 0, 0, 512, 1, 0);
  launch_gemm(stream, S2, dec_res_w + 262144, dec_res_b + 512,  nullptr, S0, 2048, 512, 512, 1, 0, 0, 0, 1, 0, 0, 512, 1, 0);
  launch_gemm(stream, S0, dec_res_w + 524288, dec_res_b + 1024, S1,      S2, 2048, 512, 512, 1, 0, 0, 0, 1, 0, 0, 512, 1, 0);
  if (full) {
    launch_gemm(stream, S2, dec_in_w, dec_in_b, nullptr, QKVb, 2048, 512, 1536, 0, 0, 0, 0, 1, 0, 0, 512, 1, 0);
    attn_k<<<dim3(4, 64), 256, 0, stream>>>(QKVb, S0, 256, 0);
  } else {
    for (int it = 0; it < 2; it++) {
      launch_gemm(stream, S2 + (size_t)it * 1024 * 512, dec_in_w, dec_in_b, nullptr, QKVb,
                  1024, 512, 1536, 0, 0, 0, 0, 1, 0, 0, 512, 1, 0);
      attn_k<<<dim3(4, 32), 256, 0, stream>>>(QKVb, S0, 256, it * 4);
    }
  }
  launch_gemm(stream, S0, dec_out_w, dec_out_b, S2, S1, 2048, 512, 512, 0, 0, 0, 0, 1, 0, 0, 512, 1, 0);
  ln_k<<<512, 256, 0, stream>>>(S1, dec_ln_g, dec_ln_b, S2);
  launch_gemm(stream, S2, dec_up_w, dec_up_b, nullptr, S0, 2048, 512, 512, 0, 0, 0, 0, 2, 0, 3, 0, 0, 0);
  launch_gemm(stream, S2, dec_up_w, dec_up_b, nullptr, S0, 2048, 512, 512, 0, 0, 0, 0, 2, 1, 3, 0, 0, 1);
  // dec block 1 (P=4096, S=512)
  launch_gemm(stream, S0, dec_res_w + 786432,  dec_res_b + 1536, nullptr, S1, 4096, 512, 512, 1, 0, 0, 0, 1, 0, 0, 512, 1, 0);
  launch_gemm(stream, S1, dec_res_w + 1048576, dec_res_b + 2048, nullptr, S2, 4096, 512, 512, 1, 0, 0, 0, 1, 0, 0, 512, 1, 0);
  launch_gemm(stream, S2, dec_res_w + 1310720, dec_res_b + 2560, S0,      S1, 4096, 512, 512, 1, 0, 0, 0, 1, 0, 0, 512, 1, 0);
  if (full) {
    launch_gemm(stream, S1, dec_in_w + 786432, dec_in_b + 1536, nullptr, QKVb, 4096, 512, 1536, 0, 0, 0, 0, 1, 0, 0, 512, 1, 0);
    attn_k<<<dim3(8, 64), 256, 0, stream>>>(QKVb, S2, 512, 0);
  } else {
    for (int it = 0; it < 4; it++) {
      launch_gemm(stream, S1 + (size_t)it * 1024 * 512, dec_in_w + 786432, dec_in_b + 1536, nullptr, QKVb,
                  1024, 512, 1536, 0, 0, 0, 0, 1, 0, 0, 512, 1, 0);
      attn_k<<<dim3(8, 16), 256, 0, stream>>>(QKVb, S2, 512, it * 2);
    }
  }
  launch_gemm(stream, S2, dec_out_w + 262144, dec_out_b + 512, S1, S0, 4096, 512, 512, 0, 0, 0, 0, 1, 0, 0, 512, 1, 0);
  ln_k<<<1024, 256, 0, stream>>>(S0, dec_ln_g + 512, dec_ln_b + 512, S1);
  launch_gemm(stream, S1, dec_up_w + 524288, dec_up_b + 512, nullptr, S0, 4096, 512, 512, 0, 0, 0, 0, 2, 0, 3, 0, 0, 0);
  launch_gemm(stream, S1, dec_up_w + 524288, dec_up_b + 512, nullptr, S0, 4096, 512, 512, 0, 0, 0, 0, 2, 1, 3, 0, 0, 1);
  // ---- log_softmax -> f32 out ----
  lsm_k<<<2048, 256, 0, stream>>>(S0, out_logp);
}

// Round 5
// 2297.018 us; speedup vs baseline: 2.8648x; 1.6917x over previous
//
#include <hip/hip_runtime.h>
#include <hip/hip_bf16.h>

// B=8 S=1024 C=512 V=512 D=512 NC=512 NF=2 H=8 TAU=1
// d_out FLOAT32: [logp 4194304][z 1048576][diff 1][ids 2048]
// ws: S0,S1,S2 (8192x512 f32) + QKV (8192x1536) + tail ~100.7 MB (proven available).
// Decoder runs bf16 MFMA; bf16 weights/activations live in the logp region of
// d_out (3,801,088 of 4,194,304 floats) and are fully overwritten by lsm_k at the end.

static constexpr size_t SLOT = 4194304; // 8192*512 floats

typedef short bf16x8 __attribute__((ext_vector_type(8)));
typedef float f32x4  __attribute__((ext_vector_type(4)));

__device__ __forceinline__ float eluf(float x) { return x > 0.f ? x : expm1f(x); }
__device__ __forceinline__ short f2bf(float v) {
  unsigned u = __float_as_uint(v);
  return (short)((u + 0x7FFFu + ((u >> 16) & 1u)) >> 16);
}

// ---------------- fp32 GEMM (encoder path) ----------------
//  wmode 0: widx = o*WS + kk*KS + woff
//  wmode 1: widx = o*1024 + (kk&511)*2 + (kk>>9)   (stride-2 k=2 downsample)
//  wmode 2: widx = kk*512 + o                      (codebook [D][NC] as [NC][D])
__global__ __launch_bounds__(256) void gemm_k(
    const float* __restrict__ A, const float* __restrict__ W,
    const float* __restrict__ bias, const float* __restrict__ res,
    float* __restrict__ Y, int P, int K, int O,
    int act, int accum, int smod, int shift, int ystride, int yoff,
    int wmode, int WS, int KS, int woff)
{
  __shared__ alignas(16) float As[16][68];
  __shared__ alignas(16) float Bs[16][68];
  const int tid = threadIdx.x;
  const int bp = blockIdx.x * 64, bo = blockIdx.y * 64;
  const int tx = tid & 15, ty = tid >> 4;
  float acc[4][4];
#pragma unroll
  for (int i = 0; i < 4; i++)
#pragma unroll
    for (int j = 0; j < 4; j++) acc[i][j] = 0.f;

  for (int k0 = 0; k0 < K; k0 += 16) {
#pragma unroll
    for (int i = 0; i < 4; i++) {
      const int idx = tid + i * 256;
      const int r = idx >> 4, kc = idx & 15;
      const int p = bp + r;
      const int kk = k0 + kc;
      float v = 0.f;
      bool ok = true;
      if (smod) { const int s = p & (smod - 1); ok = ((unsigned)(s + shift) < (unsigned)smod); }
      if (ok) v = A[(size_t)(p + shift) * K + kk];
      if (act) v = eluf(v);
      As[kc][r] = v;
      const int o = bo + r;
      size_t widx;
      if (wmode == 1)      widx = (size_t)o * 1024 + ((kk & 511) << 1) + (kk >> 9);
      else if (wmode == 2) widx = (size_t)kk * 512 + o;
      else                 widx = (size_t)o * WS + (size_t)kk * KS + woff;
      Bs[kc][r] = W[widx];
    }
    __syncthreads();
#pragma unroll
    for (int kk2 = 0; kk2 < 16; kk2++) {
      const float4 av = *(const float4*)&As[kk2][ty * 4];
      const float4 bv = *(const float4*)&Bs[kk2][tx * 4];
      const float a_[4] = {av.x, av.y, av.z, av.w};
      const float b_[4] = {bv.x, bv.y, bv.z, bv.w};
#pragma unroll
      for (int i = 0; i < 4; i++)
#pragma unroll
        for (int j = 0; j < 4; j++) acc[i][j] += a_[i] * b_[j];
    }
    __syncthreads();
  }
#pragma unroll
  for (int i = 0; i < 4; i++) {
    const int p = bp + ty * 4 + i;
    const size_t yrow = (size_t)p * ystride + yoff;
#pragma unroll
    for (int j = 0; j < 4; j++) {
      const int o = bo + tx * 4 + j;
      float v = acc[i][j];
      if (bias) v += bias[o];
      if (res)  v += res[(size_t)p * O + o];
      const size_t yi = yrow * O + o;
      if (accum) v += Y[yi];
      Y[yi] = v;
    }
  }
}

static inline void launch_gemm(hipStream_t st, const float* A, const float* W,
                               const float* bias, const float* res, float* Y,
                               int P, int K, int O, int act, int accum,
                               int smod, int shift, int ystride, int yoff,
                               int wmode, int WS, int KS, int woff)
{
  dim3 g(P / 64, O / 64);
  gemm_k<<<g, 256, 0, st>>>(A, W, bias, res, Y, P, K, O, act, accum, smod, shift,
                            ystride, yoff, wmode, WS, KS, woff);
}

// ---------------- bf16 MFMA GEMM (decoder; K fixed 512) ----------------
// A [P][512] bf16, W [O][512] bf16, Y fp32. Tile 64x64, 4 waves (2x2), each
// wave 32x32 = 2x2 fragments of mfma_f32_16x16x32_bf16. LDS XOR-swizzled.
__global__ __launch_bounds__(256) void bgemm_k(
    const short* __restrict__ A, const short* __restrict__ W,
    const float* __restrict__ bias, const float* __restrict__ res,
    float* __restrict__ Y, int P, int O, int accum,
    int smod, int shift, int ystride, int yoff)
{
  __shared__ short As[4096];
  __shared__ short Bs[4096];
  const int tid = threadIdx.x;
  const int lane = tid & 63, wid = tid >> 6;
  const int wr = wid >> 1, wc = wid & 1;
  const int bp = blockIdx.x * 64, bo = blockIdx.y * 64;
  f32x4 acc[2][2];
#pragma unroll
  for (int mi = 0; mi < 2; mi++)
#pragma unroll
    for (int ni = 0; ni < 2; ni++) acc[mi][ni] = (f32x4){0.f, 0.f, 0.f, 0.f};

  for (int k0 = 0; k0 < 512; k0 += 64) {
#pragma unroll
    for (int c0 = 0; c0 < 2; c0++) {
      const int c = tid + c0 * 256;
      const int row = c >> 3, kc = c & 7;
      int soff = (row << 6) + (kc << 3); soff ^= (row & 7) << 3;
      const int p = bp + row;
      bf16x8 av = {0, 0, 0, 0, 0, 0, 0, 0};
      bool ok = true;
      if (smod) { const int s = p & (smod - 1); ok = ((unsigned)(s + shift) < (unsigned)smod); }
      if (ok) av = *(const bf16x8*)&A[(size_t)(p + shift) * 512 + k0 + (kc << 3)];
      *(bf16x8*)&As[soff] = av;
      *(bf16x8*)&Bs[soff] = *(const bf16x8*)&W[(size_t)(bo + row) * 512 + k0 + (kc << 3)];
    }
    __syncthreads();
#pragma unroll
    for (int ks = 0; ks < 2; ks++) {
      bf16x8 af[2], bfr[2];
#pragma unroll
      for (int mi = 0; mi < 2; mi++) {
        const int row = wr * 32 + mi * 16 + (lane & 15);
        int soff = (row << 6) + (ks << 5) + ((lane >> 4) << 3);
        soff ^= (row & 7) << 3;
        af[mi] = *(const bf16x8*)&As[soff];
      }
#pragma unroll
      for (int ni = 0; ni < 2; ni++) {
        const int row = wc * 32 + ni * 16 + (lane & 15);
        int soff = (row << 6) + (ks << 5) + ((lane >> 4) << 3);
        soff ^= (row & 7) << 3;
        bfr[ni] = *(const bf16x8*)&Bs[soff];
      }
#pragma unroll
      for (int mi = 0; mi < 2; mi++)
#pragma unroll
        for (int ni = 0; ni < 2; ni++)
          acc[mi][ni] = __builtin_amdgcn_mfma_f32_16x16x32_bf16(af[mi], bfr[ni], acc[mi][ni], 0, 0, 0);
    }
    __syncthreads();
  }
#pragma unroll
  for (int mi = 0; mi < 2; mi++)
#pragma unroll
    for (int ni = 0; ni < 2; ni++)
#pragma unroll
      for (int r = 0; r < 4; r++) {
        const int p = bp + wr * 32 + mi * 16 + ((lane >> 4) << 2) + r;
        const int o = bo + wc * 32 + ni * 16 + (lane & 15);
        float v = acc[mi][ni][r];
        if (bias) v += bias[o];
        if (res)  v += res[(size_t)p * O + o];
        const size_t yi = ((size_t)p * ystride + yoff) * O + o;
        if (accum) v += Y[yi];
        Y[yi] = v;
      }
}

// ---------------- fp32 -> bf16 cast (8 elems/thread), optional ELU
__global__ __launch_bounds__(256) void cast_k(const float* __restrict__ src,
    short* __restrict__ dst, int act)
{
  const size_t i = ((size_t)blockIdx.x * 256 + threadIdx.x) * 8;
  float4 a = *(const float4*)&src[i];
  float4 b = *(const float4*)&src[i + 4];
  if (act) {
    a.x = eluf(a.x); a.y = eluf(a.y); a.z = eluf(a.z); a.w = eluf(a.w);
    b.x = eluf(b.x); b.y = eluf(b.y); b.z = eluf(b.z); b.w = eluf(b.w);
  }
  bf16x8 o;
  o[0] = f2bf(a.x); o[1] = f2bf(a.y); o[2] = f2bf(a.z); o[3] = f2bf(a.w);
  o[4] = f2bf(b.x); o[5] = f2bf(b.y); o[6] = f2bf(b.z); o[7] = f2bf(b.w);
  *(bf16x8*)&dst[i] = o;
}

// q2d_w [512 o][512 k][3] -> 3 mats [512][512] bf16 (mat w)
__global__ __launch_bounds__(256) void q2dw_k(const float* __restrict__ src, short* __restrict__ dst)
{
  const int idx = blockIdx.x * 256 + threadIdx.x; // 786432
  const int w = idx >> 18, rem = idx & 262143;
  const int o = rem >> 9, k = rem & 511;
  dst[idx] = f2bf(src[(size_t)o * 1536 + k * 3 + w]);
}

// dec_up_w [NF][512 i][512 o][2 k] -> 4 mats [(f*2+k)][512 o][512 i] bf16
__global__ __launch_bounds__(256) void upw_k(const float* __restrict__ src, short* __restrict__ dst)
{
  const int idx = blockIdx.x * 256 + threadIdx.x; // 1048576
  const int mi = idx >> 18, f = mi >> 1, kq = mi & 1;
  const int rem = idx & 262143;
  const int o = rem >> 9, i2 = rem & 511;
  dst[idx] = f2bf(src[(size_t)f * 524288 + (size_t)i2 * 1024 + o * 2 + kq]);
}

// ---------------- flash attention (fp32), register-tiled 4x4
__global__ __launch_bounds__(256) void attn_k(
    const float* __restrict__ qkv, float* __restrict__ Oa, int S, int base_b)
{
  __shared__ alignas(16) float sq[64][68];
  __shared__ alignas(16) float sk[64][68]; // reused as P^T tile
  __shared__ alignas(16) float sv[64][68];
  const int tid = threadIdx.x;
  const int bl = blockIdx.y >> 3, h = blockIdx.y & 7;
  const int q0 = blockIdx.x * 64;
  const float* base = qkv + (size_t)bl * S * 1536;
  const int qg = tid >> 4, tx = tid & 15;

#pragma unroll
  for (int i = 0; i < 16; i++) {
    const int idx = tid + i * 256;
    const int r = idx >> 6, d = idx & 63;
    sq[r][d] = base[(size_t)(q0 + r) * 1536 + h * 64 + d] * 0.125f;
  }
  float acc[4][4];
#pragma unroll
  for (int i = 0; i < 4; i++)
#pragma unroll
    for (int j = 0; j < 4; j++) acc[i][j] = 0.f;
  float m[4], l[4];
#pragma unroll
  for (int i = 0; i < 4; i++) { m[i] = -INFINITY; l[i] = 0.f; }

  for (int t0 = 0; t0 < S; t0 += 64) {
    __syncthreads();
#pragma unroll
    for (int i = 0; i < 16; i++) {
      const int idx = tid + i * 256;
      const int r = idx >> 6, d = idx & 63;
      sk[r][d] = base[(size_t)(t0 + r) * 1536 + 512 + h * 64 + d];
      sv[r][d] = base[(size_t)(t0 + r) * 1536 + 1024 + h * 64 + d];
    }
    __syncthreads();
    float s[4][4];
#pragma unroll
    for (int i = 0; i < 4; i++)
#pragma unroll
      for (int j = 0; j < 4; j++) s[i][j] = 0.f;
#pragma unroll
    for (int d4 = 0; d4 < 16; d4++) {
      float4 qv[4], kv[4];
#pragma unroll
      for (int i = 0; i < 4; i++) qv[i] = *(const float4*)&sq[qg * 4 + i][d4 * 4];
#pragma unroll
      for (int j = 0; j < 4; j++) kv[j] = *(const float4*)&sk[tx * 4 + j][d4 * 4];
#pragma unroll
      for (int i = 0; i < 4; i++)
#pragma unroll
        for (int j = 0; j < 4; j++)
          s[i][j] += qv[i].x * kv[j].x + qv[i].y * kv[j].y + qv[i].z * kv[j].z + qv[i].w * kv[j].w;
    }
    float corr[4];
#pragma unroll
    for (int i = 0; i < 4; i++) {
      float tmax = fmaxf(fmaxf(s[i][0], s[i][1]), fmaxf(s[i][2], s[i][3]));
      tmax = fmaxf(tmax, __shfl_xor(tmax, 1));
      tmax = fmaxf(tmax, __shfl_xor(tmax, 2));
      tmax = fmaxf(tmax, __shfl_xor(tmax, 4));
      tmax = fmaxf(tmax, __shfl_xor(tmax, 8));
      const float newm = fmaxf(m[i], tmax);
      corr[i] = expf(m[i] - newm);
      float psum = 0.f;
#pragma unroll
      for (int j = 0; j < 4; j++) { s[i][j] = expf(s[i][j] - newm); psum += s[i][j]; }
      psum += __shfl_xor(psum, 1);
      psum += __shfl_xor(psum, 2);
      psum += __shfl_xor(psum, 4);
      psum += __shfl_xor(psum, 8);
      l[i] = l[i] * corr[i] + psum;
      m[i] = newm;
#pragma unroll
      for (int j = 0; j < 4; j++) acc[i][j] *= corr[i];
    }
    __syncthreads(); // all done reading sk as K
#pragma unroll
    for (int j = 0; j < 4; j++)
      *(float4*)&sk[tx * 4 + j][qg * 4] = make_float4(s[0][j], s[1][j], s[2][j], s[3][j]);
    __syncthreads();
#pragma unroll
    for (int kk = 0; kk < 64; kk++) {
      const float4 p4 = *(const float4*)&sk[kk][qg * 4];
      const float4 v4 = *(const float4*)&sv[kk][tx * 4];
      const float p_[4] = {p4.x, p4.y, p4.z, p4.w};
      const float v_[4] = {v4.x, v4.y, v4.z, v4.w};
#pragma unroll
      for (int i = 0; i < 4; i++)
#pragma unroll
        for (int j = 0; j < 4; j++) acc[i][j] += p_[i] * v_[j];
    }
  }
#pragma unroll
  for (int i = 0; i < 4; i++) {
    const float inv = 1.f / l[i];
    float4* op = (float4*)&Oa[(size_t)((base_b + bl) * S + q0 + qg * 4 + i) * 512 + h * 64 + tx * 4];
    *op = make_float4(acc[i][0] * inv, acc[i][1] * inv, acc[i][2] * inv, acc[i][3] * inv);
  }
}

// ---------------- layernorm over C=512, one wave per row
__global__ __launch_bounds__(256) void ln_k(const float* __restrict__ X,
    const float* __restrict__ g, const float* __restrict__ bta,
    float* __restrict__ Y)
{
  const int row = blockIdx.x * 4 + (threadIdx.x >> 6);
  const int lane = threadIdx.x & 63;
  const float* x = X + (size_t)row * 512;
  float v[8]; float s = 0.f;
#pragma unroll
  for (int i = 0; i < 8; i++) { v[i] = x[lane + i * 64]; s += v[i]; }
#pragma unroll
  for (int off = 1; off < 64; off <<= 1) s += __shfl_xor(s, off);
  const float mean = s * (1.f / 512.f);
  float vs = 0.f;
#pragma unroll
  for (int i = 0; i < 8; i++) { const float d = v[i] - mean; vs += d * d; }
#pragma unroll
  for (int off = 1; off < 64; off <<= 1) vs += __shfl_xor(vs, off);
  const float rstd = 1.f / sqrtf(vs * (1.f / 512.f) + 1e-5f);
  float* y = Y + (size_t)row * 512;
#pragma unroll
  for (int i = 0; i < 8; i++) {
    const int c = lane + i * 64;
    y[c] = (v[i] - mean) * rstd * g[c] + bta[c];
  }
}

// ---------------- log_softmax over C=512 -> f32 out
__global__ __launch_bounds__(256) void lsm_k(const float* __restrict__ X,
    float* __restrict__ out)
{
  const int row = blockIdx.x * 4 + (threadIdx.x >> 6);
  const int lane = threadIdx.x & 63;
  const float* x = X + (size_t)row * 512;
  float v[8]; float mx = -3.0e38f;
#pragma unroll
  for (int i = 0; i < 8; i++) { v[i] = x[lane + i * 64]; mx = fmaxf(mx, v[i]); }
#pragma unroll
  for (int off = 1; off < 64; off <<= 1) mx = fmaxf(mx, __shfl_xor(mx, off));
  float sum = 0.f;
#pragma unroll
  for (int i = 0; i < 8; i++) sum += expf(v[i] - mx);
#pragma unroll
  for (int off = 1; off < 64; off <<= 1) sum += __shfl_xor(sum, off);
  const float ls = logf(sum);
  float* y = out + (size_t)row * 512;
#pragma unroll
  for (int i = 0; i < 8; i++) y[lane + i * 64] = v[i] - mx - ls;
}

// ---------------- embedding gather
__global__ __launch_bounds__(256) void embed_k(const int* __restrict__ x,
    const float* __restrict__ emb, float* __restrict__ out)
{
  const int i = blockIdx.x * 256 + threadIdx.x;
  const int p = i >> 7, c4 = i & 127;
  const int id = x[p];
  *(float4*)&out[(size_t)p * 512 + c4 * 4] = *(const float4*)&emb[(size_t)id * 512 + c4 * 4];
}

// ---------------- codebook column norms (codebook is [D][NC])
__global__ __launch_bounds__(64) void cnorm_k(const float* __restrict__ cb, float* __restrict__ cn)
{
  const int n = blockIdx.x; const int lane = threadIdx.x;
  float s = 0.f;
#pragma unroll
  for (int i = 0; i < 8; i++) {
    const float v = cb[(size_t)(lane + i * 64) * 512 + n];
    s += v * v;
  }
#pragma unroll
  for (int off = 1; off < 64; off <<= 1) s += __shfl_xor(s, off);
  if (lane == 0) cn[n] = s;
}

// ---------------- VQ argmin
__global__ __launch_bounds__(256) void argmin_k(const float* __restrict__ scores,
    const float* __restrict__ cn, int* __restrict__ ids,
    float* __restrict__ out_ids)
{
  const int row = blockIdx.x * 4 + (threadIdx.x >> 6);
  const int lane = threadIdx.x & 63;
  const float* sr = scores + (size_t)row * 512;
  float best = 3.0e38f; int bi = 0x7fffffff;
#pragma unroll
  for (int i = 0; i < 8; i++) {
    const int n = lane + i * 64;
    const float v = cn[n] - 2.f * sr[n];
    if (v < best || (v == best && n < bi)) { best = v; bi = n; }
  }
#pragma unroll
  for (int off = 1; off < 64; off <<= 1) {
    const float ov = __shfl_xor(best, off);
    const int oi = __shfl_xor(bi, off);
    if (ov < best || (ov == best && oi < bi)) { best = ov; bi = oi; }
  }
  if (lane == 0) { ids[row] = bi; out_ids[row] = (float)bi; }
}

// ---------------- z = z_e + (q - z_e) -> out_z; diff partials
__global__ __launch_bounds__(128) void zq_k(const float* __restrict__ z_e,
    const float* __restrict__ cb, const int* __restrict__ ids,
    float* __restrict__ zout, float* __restrict__ dpart)
{
  __shared__ float red[2];
  const int p = blockIdx.x, t = threadIdx.x;
  const int id = ids[p];
  const float4 ze = *(const float4*)&z_e[(size_t)p * 512 + t * 4];
  const float q0 = cb[(size_t)(t * 4 + 0) * 512 + id];
  const float q1 = cb[(size_t)(t * 4 + 1) * 512 + id];
  const float q2 = cb[(size_t)(t * 4 + 2) * 512 + id];
  const float q3 = cb[(size_t)(t * 4 + 3) * 512 + id];
  const float4 dv = make_float4(q0 - ze.x, q1 - ze.y, q2 - ze.z, q3 - ze.w);
  const float4 z  = make_float4(ze.x + dv.x, ze.y + dv.y, ze.z + dv.z, ze.w + dv.w);
  *(float4*)&zout[(size_t)p * 512 + t * 4] = z;
  float loc = dv.x * dv.x + dv.y * dv.y + dv.z * dv.z + dv.w * dv.w;
#pragma unroll
  for (int off = 1; off < 64; off <<= 1) loc += __shfl_xor(loc, off);
  const int lane = t & 63, w = t >> 6;
  if (lane == 0) red[w] = loc;
  __syncthreads();
  if (t == 0) dpart[p] = red[0] + red[1];
}

__global__ __launch_bounds__(256) void diffred_k(const float* __restrict__ dpart,
    float* __restrict__ out_diff)
{
  __shared__ float red[4];
  const int t = threadIdx.x;
  float s = 0.f;
#pragma unroll
  for (int i = 0; i < 8; i++) s += dpart[t + i * 256];
#pragma unroll
  for (int off = 1; off < 64; off <<= 1) s += __shfl_xor(s, off);
  if ((t & 63) == 0) red[t >> 6] = s;
  __syncthreads();
  if (t == 0) out_diff[0] = (red[0] + red[1] + red[2] + red[3]) * (1.f / 1048576.f);
}

// =====================================================================
extern "C" void kernel_launch(void* const* d_in, const int* in_sizes, int n_in,
                              void* d_out, int out_size, void* d_ws, size_t ws_size,
                              hipStream_t stream)
{
  const int*   x         = (const int*)d_in[0];
  const float* embed     = (const float*)d_in[1];
  const float* enc_res_w = (const float*)d_in[2];
  const float* enc_res_b = (const float*)d_in[3];
  const float* enc_in_w  = (const float*)d_in[4];
  const float* enc_in_b  = (const float*)d_in[5];
  const float* enc_out_w = (const float*)d_in[6];
  const float* enc_out_b = (const float*)d_in[7];
  const float* enc_ln_g  = (const float*)d_in[8];
  const float* enc_ln_b  = (const float*)d_in[9];
  const float* enc_down_w= (const float*)d_in[10];
  const float* enc_down_b= (const float*)d_in[11];
  const float* e2q_w     = (const float*)d_in[12];
  const float* e2q_b     = (const float*)d_in[13];
  const float* codebook  = (const float*)d_in[14];
  const float* q2d_w     = (const float*)d_in[15];
  const float* q2d_b     = (const float*)d_in[16];
  const float* dec_res_w = (const float*)d_in[17];
  const float* dec_res_b = (const float*)d_in[18];
  const float* dec_in_w  = (const float*)d_in[19];
  const float* dec_in_b  = (const float*)d_in[20];
  const float* dec_out_w = (const float*)d_in[21];
  const float* dec_out_b = (const float*)d_in[22];
  const float* dec_ln_g  = (const float*)d_in[23];
  const float* dec_ln_b  = (const float*)d_in[24];
  const float* dec_up_w  = (const float*)d_in[25];
  const float* dec_up_b  = (const float*)d_in[26];

  float* ws = (float*)d_ws;
  float* S0   = ws;
  float* S1   = ws + SLOT;
  float* S2   = ws + 2 * SLOT;
  float* QKVb = ws + 3 * SLOT;               // 8192*1536 floats
  float* cnorm = QKVb + (size_t)8192 * 1536; // [512]
  int*   idsI  = (int*)(cnorm + 512);        // [2048]
  float* dpart = (float*)(idsI + 2048);      // [2048]

  float* out      = (float*)d_out;           // FLOAT32 output buffer
  float* out_logp = out;                     // 4194304
  float* out_z    = out + 4194304;           // 1048576
  float* out_diff = out + 5242880;           // 1
  float* out_ids  = out + 5242881;           // 2048

  // bf16 scratch inside logp region (fully overwritten by lsm_k at the end)
  short* q2dWb = (short*)out_logp;           // 3*262144
  short* resWb = q2dWb + 786432;             // 6*262144
  short* inWb  = resWb + 1572864;            // 2*786432
  short* outWb = inWb + 1572864;             // 2*262144
  short* upWb  = outWb + 524288;             // 4*262144
  short* Ab    = upWb + 1048576;             // up to 4096*512
  // total shorts: 5505024 + 2097152 = 7602176 = 3801088 floats < 4194304 OK

  // ---- decoder weight conversions ----
  q2dw_k<<<3072, 256, 0, stream>>>(q2d_w, q2dWb);
  cast_k<<<768, 256, 0, stream>>>(dec_res_w, resWb, 0);   // 6*262144 = 1572864
  cast_k<<<768, 256, 0, stream>>>(dec_in_w,  inWb, 0);    // 1572864
  cast_k<<<256, 256, 0, stream>>>(dec_out_w, outWb, 0);   // 524288
  upw_k<<<4096, 256, 0, stream>>>(dec_up_w, upWb);
  cnorm_k<<<512, 64, 0, stream>>>(codebook, cnorm);

  // ---- encoder (fp32) ----
  embed_k<<<4096, 256, 0, stream>>>(x, embed, S0);
  launch_gemm(stream, S0, enc_res_w,          enc_res_b,        nullptr, S1, 8192, 512, 512, 1, 0, 0, 0, 1, 0, 0, 512, 1, 0);
  launch_gemm(stream, S1, enc_res_w + 262144, enc_res_b + 512,  nullptr, S2, 8192, 512, 512, 1, 0, 0, 0, 1, 0, 0, 512, 1, 0);
  launch_gemm(stream, S2, enc_res_w + 524288, enc_res_b + 1024, S0,      S1, 8192, 512, 512, 1, 0, 0, 0, 1, 0, 0, 512, 1, 0);
  launch_gemm(stream, S1, enc_in_w, enc_in_b, nullptr, QKVb, 8192, 512, 1536, 0, 0, 0, 0, 1, 0, 0, 512, 1, 0);
  attn_k<<<dim3(16, 64), 256, 0, stream>>>(QKVb, S2, 1024, 0);
  launch_gemm(stream, S2, enc_out_w, enc_out_b, S1, S0, 8192, 512, 512, 0, 0, 0, 0, 1, 0, 0, 512, 1, 0);
  ln_k<<<2048, 256, 0, stream>>>(S0, enc_ln_g, enc_ln_b, S1);
  launch_gemm(stream, S1, enc_down_w,          enc_down_b,       nullptr, S2, 4096, 1024, 512, 0, 0, 0, 0, 1, 0, 1, 0, 0, 0);
  launch_gemm(stream, S2, enc_down_w + 524288, enc_down_b + 512, nullptr, S0, 2048, 1024, 512, 0, 0, 0, 0, 1, 0, 1, 0, 0, 0);
  launch_gemm(stream, S0, e2q_w, e2q_b,   nullptr, S2, 2048, 512, 512, 0, 0, 256, -1, 1, 0, 0, 1536, 3, 0);
  launch_gemm(stream, S0, e2q_w, nullptr, nullptr, S2, 2048, 512, 512, 0, 1, 256,  0, 1, 0, 0, 1536, 3, 1);
  launch_gemm(stream, S0, e2q_w, nullptr, nullptr, S2, 2048, 512, 512, 0, 1, 256,  1, 1, 0, 0, 1536, 3, 2);
  // ---- VQ (fp32, exact) ----
  launch_gemm(stream, S2, codebook, nullptr, nullptr, S1, 2048, 512, 512, 0, 0, 0, 0, 1, 0, 2, 0, 0, 0);
  argmin_k<<<512, 256, 0, stream>>>(S1, cnorm, idsI, out_ids);
  zq_k<<<2048, 128, 0, stream>>>(S2, codebook, idsI, out_z, dpart);
  diffred_k<<<1, 256, 0, stream>>>(dpart, out_diff);

  // ---- decoder (bf16 MFMA) ----
  // q2d: conv k3 pad1 on z
  cast_k<<<512, 256, 0, stream>>>(out_z, Ab, 0);          // 2048*512
  { dim3 g(32, 8);
    bgemm_k<<<g, 256, 0, stream>>>(Ab, q2dWb,           q2d_b,  nullptr, S1, 2048, 512, 0, 256, -1, 1, 0);
    bgemm_k<<<g, 256, 0, stream>>>(Ab, q2dWb + 262144,  nullptr, nullptr, S1, 2048, 512, 1, 256,  0, 1, 0);
    bgemm_k<<<g, 256, 0, stream>>>(Ab, q2dWb + 524288,  nullptr, nullptr, S1, 2048, 512, 1, 256,  1, 1, 0);
  }
  // dec block 0 (P=2048, S=256)
  { dim3 g(32, 8); dim3 gq(32, 24);
    cast_k<<<512, 256, 0, stream>>>(S1, Ab, 1);
    bgemm_k<<<g, 256, 0, stream>>>(Ab, resWb,            dec_res_b,        nullptr, S2, 2048, 512, 0, 0, 0, 1, 0);
    cast_k<<<512, 256, 0, stream>>>(S2, Ab, 1);
    bgemm_k<<<g, 256, 0, stream>>>(Ab, resWb + 262144,   dec_res_b + 512,  nullptr, S0, 2048, 512, 0, 0, 0, 1, 0);
    cast_k<<<512, 256, 0, stream>>>(S0, Ab, 1);
    bgemm_k<<<g, 256, 0, stream>>>(Ab, resWb + 524288,   dec_res_b + 1024, S1,      S2, 2048, 512, 0, 0, 0, 1, 0);
    cast_k<<<512, 256, 0, stream>>>(S2, Ab, 0);
    bgemm_k<<<gq, 256, 0, stream>>>(Ab, inWb,            dec_in_b,         nullptr, QKVb, 2048, 1536, 0, 0, 0, 1, 0);
    attn_k<<<dim3(4, 64), 256, 0, stream>>>(QKVb, S0, 256, 0);
    cast_k<<<512, 256, 0, stream>>>(S0, Ab, 0);
    bgemm_k<<<g, 256, 0, stream>>>(Ab, outWb,            dec_out_b,        S2, S1, 2048, 512, 0, 0, 0, 1, 0);
    ln_k<<<512, 256, 0, stream>>>(S1, dec_ln_g, dec_ln_b, S2);
    cast_k<<<512, 256, 0, stream>>>(S2, Ab, 0);
    bgemm_k<<<g, 256, 0, stream>>>(Ab, upWb,             dec_up_b, nullptr, S0, 2048, 512, 0, 0, 0, 2, 0);
    bgemm_k<<<g, 256, 0, stream>>>(Ab, upWb + 262144,    dec_up_b, nullptr, S0, 2048, 512, 0, 0, 0, 2, 1);
  }
  // dec block 1 (P=4096, S=512)
  { dim3 g(64, 8); dim3 gq(64, 24);
    cast_k<<<1024, 256, 0, stream>>>(S0, Ab, 1);
    bgemm_k<<<g, 256, 0, stream>>>(Ab, resWb + 786432,   dec_res_b + 1536, nullptr, S1, 4096, 512, 0, 0, 0, 1, 0);
    cast_k<<<1024, 256, 0, stream>>>(S1, Ab, 1);
    bgemm_k<<<g, 256, 0, stream>>>(Ab, resWb + 1048576,  dec_res_b + 2048, nullptr, S2, 4096, 512, 0, 0, 0, 1, 0);
    cast_k<<<1024, 256, 0, stream>>>(S2, Ab, 1);
    bgemm_k<<<g, 256, 0, stream>>>(Ab, resWb + 1310720,  dec_res_b + 2560, S0,      S1, 4096, 512, 0, 0, 0, 1, 0);
    cast_k<<<1024, 256, 0, stream>>>(S1, Ab, 0);
    bgemm_k<<<gq, 256, 0, stream>>>(Ab, inWb + 786432,   dec_in_b + 1536,  nullptr, QKVb, 4096, 1536, 0, 0, 0, 1, 0);
    attn_k<<<dim3(8, 64), 256, 0, stream>>>(QKVb, S2, 512, 0);
    cast_k<<<1024, 256, 0, stream>>>(S2, Ab, 0);
    bgemm_k<<<g, 256, 0, stream>>>(Ab, outWb + 262144,   dec_out_b + 512,  S1, S0, 4096, 512, 0, 0, 0, 1, 0);
    ln_k<<<1024, 256, 0, stream>>>(S0, dec_ln_g + 512, dec_ln_b + 512, S1);
    cast_k<<<1024, 256, 0, stream>>>(S1, Ab, 0);
    bgemm_k<<<g, 256, 0, stream>>>(Ab, upWb + 524288,    dec_up_b + 512, nullptr, S0, 4096, 512, 0, 0, 0, 2, 0);
    bgemm_k<<<g, 256, 0, stream>>>(Ab, upWb + 786432,    dec_up_b + 512, nullptr, S0, 4096, 512, 0, 0, 0, 2, 1);
  }
  // ---- log_softmax -> f32 out (overwrites bf16 scratch region) ----
  lsm_k<<<2048, 256, 0, stream>>>(S0, out_logp);
}